// Round 11
// baseline (90.325 us; speedup 1.0000x reference)
//
#include <hip/hip_runtime.h>
#include <hip/hip_bf16.h>

// NT-Xent loss, N=4096, Z=128, T=0.5.
//
// Round 4: scratch in MFMA-FRAGMENT ORDER -> coalesced dwordx4 frag loads.
// Round 7 (23.4us k_simsum): bf16, 64-row waves, 512 blocks = 2/CU,
// reg-double-buffered B. Round 10: pipelined epilogue = neutral -> not
// epilogue-bound. Model: per-SIMD ideal ~7us vs 23.4 measured -> overlap
// deficit at 2 waves/SIMD. Rounds 8/9 (fp8) likely lost to >128 regs ->
// 3 blocks/CU -> ragged 1.33 dispatch rounds, not dtype.
// Round 11: 4 WAVES/SIMD at unchanged arithmetic intensity. 64-row waves,
// 16-col steps: afrag 64 + bfrag 16 (single buf) + acc 16 + rowsum 16
// ~= 120 regs <= 128 -> 4 blocks/CU, grid 1024 = one even round.
// Per iteration: issue loads(g), run epi(g-1) VALU under the load latency,
// then MFMA(g) — zero-extra-register pipeline; cross-wave TLP covers rest.
//
// pack layout (16 B granules): pack[(G*4+ks)*64 + q*16 + n] = rows G*16+n,
// k in [ks*32+q*8, +8)  -> A/B frag load = dwordx4 at (G*4+ks)*512 + lane*8.

#define N_PAIRS 4096
#define ZDIM    128
#define NROWS   8192
#define QS 1.6986437717f   // sqrt(2 * log2(e)) ; folds 1/T=2 and exp->exp2

typedef __bf16 bf16x8 __attribute__((ext_vector_type(8)));
typedef float  floatx4 __attribute__((ext_vector_type(4)));

__global__ __launch_bounds__(256) void k_normalize(
    const float* __restrict__ z1, const float* __restrict__ z2,
    __hip_bfloat16* __restrict__ pack, float* __restrict__ pos,
    float* __restrict__ denom)
{
    const int zi = blockIdx.x * 256 + threadIdx.x;   // grid 1024 blocks; 32 zero denom
    if (zi < NROWS) denom[zi] = 0.0f;

    const int w = threadIdx.x >> 6;
    const int lane = threadIdx.x & 63;
    const int p = blockIdx.x * 4 + w;            // pair index, < 4096
    const float2 a = ((const float2*)(z1 + (size_t)p * ZDIM))[lane];
    const float2 b = ((const float2*)(z2 + (size_t)p * ZDIM))[lane];
    float s1 = a.x * a.x + a.y * a.y;
    float s2 = b.x * b.x + b.y * b.y;
    float d  = a.x * b.x + a.y * b.y;
    #pragma unroll
    for (int off = 1; off < 64; off <<= 1) {
        s1 += __shfl_xor(s1, off, 64);
        s2 += __shfl_xor(s2, off, 64);
        d  += __shfl_xor(d,  off, 64);
    }
    const float n1 = fmaxf(sqrtf(s1), 1e-8f);
    const float n2 = fmaxf(sqrtf(s2), 1e-8f);
    const float i1 = 1.0f / n1, i2 = 1.0f / n2;
    const float q1 = i1 * QS, q2 = i2 * QS;
    float2 na; na.x = a.x * q1; na.y = a.y * q1;
    float2 nb; nb.x = b.x * q2; nb.y = b.y * q2;

    // lane holds elements e0=2*lane, e0+1 of its row:
    //   ks = lane>>4 ; q = (lane>>2)&3 ; j = (lane&3)*2
    // pack elem idx for row r: ((r>>4)*4 + ks)*512 + q*128 + (r&15)*8 + j
    const int ks = lane >> 4;
    const int qq = (lane >> 2) & 3;
    const int jj = (lane & 3) * 2;
    const int r1 = p, r2 = p + N_PAIRS;
    const size_t i1e = ((size_t)((r1 >> 4) * 4 + ks)) * 512 + qq * 128 + (r1 & 15) * 8 + jj;
    const size_t i2e = ((size_t)((r2 >> 4) * 4 + ks)) * 512 + qq * 128 + (r2 & 15) * 8 + jj;
    *(__hip_bfloat162*)(pack + i1e) = __float22bfloat162_rn(na);
    *(__hip_bfloat162*)(pack + i2e) = __float22bfloat162_rn(nb);
    if (lane == 0) pos[p] = d * i1 * i2;
}

// Block: 256 thr = 4 waves stacked vertically; wave w owns 64 rows
// [rt*256 + w*64, +64). Block tile 256 rows x 256 cols, swept in 16 steps
// of 16 cols. Grid = 32 rt x 32 cs = 1024 blocks = 4 blocks/CU
// (requires <=128 VGPR; footprint ~120), one even dispatch round.
__global__ __launch_bounds__(256) void k_simsum(
    const __hip_bfloat16* __restrict__ pack, float* __restrict__ denom)
{
    const int tid  = threadIdx.x;
    const int lane = tid & 63;
    const int w    = tid >> 6;
    const int rt   = blockIdx.x >> 5;   // row tile [0,32)
    const int cs   = blockIdx.x & 31;   // col slab [0,32)
    const int q    = lane >> 4;         // quad 0..3
    const int l16  = lane & 15;

    // ---- persistent A fragments: wave's 64 rows x full K=128 (64 VGPRs) ----
    const int rowb = rt * 256 + w * 64;
    const __hip_bfloat16* Abase =
        pack + ((size_t)(rowb >> 4) * 4) * 512 + lane * 8;
    bf16x8 afrag[4][4];                  // [mt][ks]
    #pragma unroll
    for (int mt = 0; mt < 4; ++mt)
        #pragma unroll
        for (int ks = 0; ks < 4; ++ks)
            afrag[mt][ks] = *(const bf16x8*)(Abase + mt * 2048 + ks * 512);

    float rowsum[4][4];                  // [mt][r]
    #pragma unroll
    for (int mt = 0; mt < 4; ++mt)
        #pragma unroll
        for (int r = 0; r < 4; ++r) rowsum[mt][r] = 0.0f;

    // B base for this 256-col slab; step g covers cols cs*256+g*16..+16,
    // one granule-group of 4 ks x 512 elems = 2048 elems per step.
    const __hip_bfloat16* Bcol0 =
        pack + ((size_t)(cs * 16) * 4) * 512 + lane * 8;

    bf16x8  bfrag[4];                    // [ks], single buffer (16 regs)
    floatx4 acc[4];                      // [mt] (16 regs)

    auto loadB = [&](int g) {
        const __hip_bfloat16* bp = Bcol0 + (size_t)g * 2048;
        #pragma unroll
        for (int ks = 0; ks < 4; ++ks)
            bfrag[ks] = *(const bf16x8*)(bp + ks * 512);
    };
    auto mfma_step = [&]() {
        #pragma unroll
        for (int mt = 0; mt < 4; ++mt) {
            acc[mt].x = 0.f; acc[mt].y = 0.f; acc[mt].z = 0.f; acc[mt].w = 0.f;
        }
        #pragma unroll
        for (int ks = 0; ks < 4; ++ks)
            #pragma unroll
            for (int mt = 0; mt < 4; ++mt)
                acc[mt] = __builtin_amdgcn_mfma_f32_16x16x32_bf16(
                    afrag[mt][ks], bfrag[ks], acc[mt], 0, 0, 0);
    };
    // fused epilogue: bare exp2 + row-sum.
    // C/D layout: col = l16, row = q*4 + r (m89/m91 verified)
    auto epi = [&](int g) {
        const int colb = cs * 256 + g * 16;
        #pragma unroll
        for (int mt = 0; mt < 4; ++mt) {
            const int rowtb = rowb + mt * 16;
            if (rowtb == colb) {             // wave-uniform: diagonal tile
                #pragma unroll
                for (int r = 0; r < 4; ++r) {
                    const float e = __builtin_amdgcn_exp2f(acc[mt][r]);
                    rowsum[mt][r] += (l16 == q * 4 + r) ? 0.0f : e;
                }
            } else {
                #pragma unroll
                for (int r = 0; r < 4; ++r)
                    rowsum[mt][r] += __builtin_amdgcn_exp2f(acc[mt][r]);
            }
        }
    };

    // ---- main sweep: 16 steps of 16 cols ----
    // Iteration order: [issue loads g][epi g-1 under load latency][mfma g]
    loadB(0);
    mfma_step();
    for (int g = 1; g < 16; ++g) {
        loadB(g);          // issue VMEM first
        epi(g - 1);        // ~180 cyc VALU hides the load latency
        mfma_step();       // consumes bfrag(g), re-zeroes acc after epi read
    }
    epi(15);

    // ---- row-sum reduction: across the 16 lanes holding the same row ----
    #pragma unroll
    for (int mt = 0; mt < 4; ++mt)
        #pragma unroll
        for (int r = 0; r < 4; ++r) {
            float s = rowsum[mt][r];
            s += __shfl_xor(s, 1, 64);
            s += __shfl_xor(s, 2, 64);
            s += __shfl_xor(s, 4, 64);
            s += __shfl_xor(s, 8, 64);
            rowsum[mt][r] = s;
        }
    if (l16 == 0) {
        #pragma unroll
        for (int mt = 0; mt < 4; ++mt)
            #pragma unroll
            for (int r = 0; r < 4; ++r) {
                const int grow = rowb + mt * 16 + q * 4 + r;
                atomicAdd(&denom[grow], rowsum[mt][r]);
            }
    }
}

__global__ __launch_bounds__(1024) void k_finish(
    const float* __restrict__ denom, const float* __restrict__ pos,
    float* __restrict__ out)
{
    __shared__ float red[16];
    const int t = threadIdx.x;
    const int lane = t & 63, wv = t >> 6;
    float s = 0.0f;
    for (int i = t; i < NROWS; i += 1024) s += __logf(denom[i]);
    float p = 0.0f;
    for (int i = t; i < N_PAIRS; i += 1024) p += pos[i];
    float v = s - 4.0f * p;   // sum_i pos_i/T over 2N rows = 4 * sum_p cos_p
    #pragma unroll
    for (int off = 1; off < 64; off <<= 1) v += __shfl_xor(v, off, 64);
    if (lane == 0) red[wv] = v;
    __syncthreads();
    if (wv == 0) {
        float x = (lane < 16) ? red[lane] : 0.0f;
        #pragma unroll
        for (int off = 1; off < 16; off <<= 1) x += __shfl_xor(x, off, 64);
        if (lane == 0) out[0] = x / (float)NROWS;
    }
}

extern "C" void kernel_launch(void* const* d_in, const int* in_sizes, int n_in,
                              void* d_out, int out_size, void* d_ws, size_t ws_size,
                              hipStream_t stream) {
    const float* z1 = (const float*)d_in[0];
    const float* z2 = (const float*)d_in[1];
    float* out = (float*)d_out;

    char* ws = (char*)d_ws;
    __hip_bfloat16* pack = (__hip_bfloat16*)ws;                // 2 MB
    float* denom = (float*)(ws + (size_t)NROWS * ZDIM * 2);    // 32 KB
    float* pos   = denom + NROWS;                              // 16 KB

    k_normalize<<<N_PAIRS / 4, 256, 0, stream>>>(z1, z2, pack, pos, denom);
    k_simsum<<<1024, 256, 0, stream>>>(pack, denom);
    k_finish<<<1, 1024, 0, stream>>>(denom, pos, out);
}